// Round 3
// baseline (240.594 us; speedup 1.0000x reference)
//
#include <hip/hip_runtime.h>
#include <hip/hip_bf16.h>
#include <stdint.h>
#include <math.h>

#define NTOK 4096
#define DIM 768
#define FF 3072
#define NE 4

typedef __attribute__((ext_vector_type(8))) short bf16x8;
typedef __attribute__((ext_vector_type(4))) float f32x4;
typedef unsigned short u16;

static __device__ __forceinline__ u16 f2bf(float f) {
    union { float f; unsigned u; } c; c.f = f;
    unsigned r = (c.u + 0x7FFFu + ((c.u >> 16) & 1u)) >> 16;
    return (u16)r;
}

// Abramowitz-Stegun 7.1.26, |abs err| <= 1.5e-7 (beyond bf16 grain)
static __device__ __forceinline__ float fast_erff(float x) {
    float ax = fabsf(x);
    float t = 1.0f / (1.0f + 0.3275911f * ax);
    float p = ((((1.061405429f * t - 1.453152027f) * t) + 1.421413741f) * t
               - 0.284496736f) * t + 0.254829592f;
    float y = 1.0f - p * t * __expf(-ax * ax);
    return copysignf(y, x);
}

#define GLD_LDS16(g, l) __builtin_amdgcn_global_load_lds( \
    (const __attribute__((address_space(1))) void*)(g),   \
    (__attribute__((address_space(3))) void*)(l), 16, 0, 0)

// ---------------- gating: logits, softmax, argmax, token lists ----------------
__global__ __launch_bounds__(256) void gate_kernel(
    const float* __restrict__ x, const float* __restrict__ gw,
    float* __restrict__ probs, int* __restrict__ counts, int* __restrict__ tlist,
    int* __restrict__ eid)
{
    const int wid = threadIdx.x >> 6, lane = threadIdx.x & 63;
    const int n = blockIdx.x * 4 + wid;
    const float* xr = x + (size_t)n * DIM;
    float a0 = 0.f, a1 = 0.f, a2 = 0.f, a3 = 0.f;
    for (int d = lane; d < DIM; d += 64) {
        float xv = xr[d];
        a0 += xv * gw[0 * DIM + d];
        a1 += xv * gw[1 * DIM + d];
        a2 += xv * gw[2 * DIM + d];
        a3 += xv * gw[3 * DIM + d];
    }
    #pragma unroll
    for (int off = 32; off > 0; off >>= 1) {
        a0 += __shfl_xor(a0, off);
        a1 += __shfl_xor(a1, off);
        a2 += __shfl_xor(a2, off);
        a3 += __shfl_xor(a3, off);
    }
    if (lane == 0) {
        float l[4] = {a0, a1, a2, a3};
        float m = fmaxf(fmaxf(l[0], l[1]), fmaxf(l[2], l[3]));
        float p[4], s = 0.f;
        #pragma unroll
        for (int e = 0; e < 4; e++) { p[e] = expf(l[e] - m); s += p[e]; }
        float inv = 1.f / s;
        int amax = 0; float best = l[0];
        #pragma unroll
        for (int e = 1; e < 4; e++) if (l[e] > best) { best = l[e]; amax = e; }
        #pragma unroll
        for (int e = 0; e < 4; e++) probs[n * 4 + e] = p[e] * inv;
        eid[n] = amax;
        int pos = atomicAdd(&counts[amax], 1);
        tlist[amax * NTOK + pos] = n;
    }
}

// ---------------- balance loss + gate_load tail outputs ----------------
__global__ __launch_bounds__(256) void finalize_kernel(
    const float4* __restrict__ probs4, const int* __restrict__ counts,
    float* __restrict__ tail)
{
    __shared__ float sdata[256 * 4];
    float p0 = 0.f, p1 = 0.f, p2 = 0.f, p3 = 0.f;
    for (int n = threadIdx.x; n < NTOK; n += 256) {
        float4 v = probs4[n];
        p0 += v.x; p1 += v.y; p2 += v.z; p3 += v.w;
    }
    sdata[threadIdx.x * 4 + 0] = p0;
    sdata[threadIdx.x * 4 + 1] = p1;
    sdata[threadIdx.x * 4 + 2] = p2;
    sdata[threadIdx.x * 4 + 3] = p3;
    __syncthreads();
    for (int s = 128; s > 0; s >>= 1) {
        if ((int)threadIdx.x < s) {
            #pragma unroll
            for (int e = 0; e < 4; e++)
                sdata[threadIdx.x * 4 + e] += sdata[(threadIdx.x + s) * 4 + e];
        }
        __syncthreads();
    }
    if (threadIdx.x == 0) {
        float bl = 0.f;
        #pragma unroll
        for (int e = 0; e < 4; e++)
            bl += (sdata[e] / (float)NTOK) * ((float)counts[e] / (float)NTOK);
        bl *= (float)NE;
        tail[0] = bl;
        #pragma unroll
        for (int e = 0; e < 4; e++) tail[1 + e] = (float)counts[e];
    }
}

// ---------------- fp32 -> bf16 elementwise ----------------
__global__ __launch_bounds__(256) void convert_x_kernel(
    const float4* __restrict__ in, u16* __restrict__ out)
{
    int i = blockIdx.x * 256 + threadIdx.x;
    float4 v = in[i];
    ushort4 o;
    o.x = f2bf(v.x); o.y = f2bf(v.y); o.z = f2bf(v.z); o.w = f2bf(v.w);
    *(ushort4*)(out + (size_t)i * 4) = o;
}

// ---- fp32 [E][R][C] -> bf16 [E][C][R] transpose, vectorized both sides ----
__global__ __launch_bounds__(256) void transpose_convert_kernel(
    const float* __restrict__ in, u16* __restrict__ out, int R, int C)
{
    __shared__ float tile[64 * 65];
    const int e = blockIdx.z;
    const float* src = in + (size_t)e * R * C;
    u16* dst = out + (size_t)e * R * C;
    const int r0 = blockIdx.y * 64, c0 = blockIdx.x * 64;
    // phase 1: 64x64 fp32, float4 loads (16B/lane)
    #pragma unroll
    for (int p = 0; p < 4; ++p) {
        int f = p * 256 + threadIdx.x;            // float4 slot
        int row = f >> 4, c4 = (f & 15) * 4;
        float4 v = *(const float4*)(src + (size_t)(r0 + row) * C + c0 + c4);
        tile[row * 65 + c4 + 0] = v.x;
        tile[row * 65 + c4 + 1] = v.y;
        tile[row * 65 + c4 + 2] = v.z;
        tile[row * 65 + c4 + 3] = v.w;
    }
    __syncthreads();
    // phase 2: each thread packs 8 input-rows of one column -> one 16B store
    #pragma unroll
    for (int p = 0; p < 2; ++p) {
        int u = p * 256 + threadIdx.x;
        int orow = u >> 3, g = (u & 7) * 8;
        bf16x8 v;
        #pragma unroll
        for (int j = 0; j < 8; ++j)
            v[j] = (short)f2bf(tile[(g + j) * 65 + orow]);
        *(bf16x8*)(dst + (size_t)(c0 + orow) * R + r0 + g) = v;
    }
}

// ---------------- out := bias row per token's expert (split-K atomic base) ----------------
__global__ __launch_bounds__(256) void init_out_kernel(
    const float* __restrict__ b2, const int* __restrict__ eid,
    float4* __restrict__ out4)
{
    int idx = blockIdx.x * 256 + threadIdx.x;   // over NTOK*DIM/4
    int n = idx / (DIM / 4);
    int c = idx % (DIM / 4);
    int e = eid[n];
    out4[idx] = ((const float4*)(b2 + (size_t)e * DIM))[c];
}

// ---------------- grouped MFMA GEMM, 128x128 tile, 4 waves, 4-deep pipeline ----------------
// Counted-vmcnt pipeline (T3+T4): per iter  { vmcnt(N) ; s_barrier ; issue stage(t+3) ;
// ds_read buf[t&3] + MFMA }.  Loads stay in flight across barriers (never vmcnt(0) in loop).
// LDS swizzle: element (r,c16) at byte (r*64+c16*16)^((r&7)<<4) per buffer.
template <int KD, int NCOL, int KSPLIT, int GELU_EP>
__global__ __launch_bounds__(256, 2) void moe_gemm(
    const u16* __restrict__ A, const u16* __restrict__ Bt,
    const float* __restrict__ bias, const int* __restrict__ counts,
    const int* __restrict__ tlist, u16* __restrict__ Hout,
    float* __restrict__ Fout)
{
    constexpr int KSUB = KD / KSPLIT;
    constexpr int NS = KSUB / 32;
    constexpr int CTN = NCOL / 128;

    // bijective XCD swizzle (grid % 8 == 0): same B-panel blocks -> same XCD L2
    const int nwg = gridDim.x;
    const int bx = blockIdx.x;
    const int work = (bx & 7) * (nwg >> 3) + (bx >> 3);
    const int rt = work & 31;
    int w2 = work >> 5;
    const int ks = w2 % KSPLIT;
    const int pc = w2 / KSPLIT;
    const int ct = pc % CTN;
    const int e = pc / CTN;

    const int cnt = counts[e];
    if (rt * 128 >= cnt) return;
    const int nvalid = min(128, cnt - rt * 128);
    const int* list = tlist + e * NTOK + rt * 128;
    const int ksoff = ks * KSUB;

    __shared__ __align__(16) u16 As[4][4096];
    __shared__ __align__(16) u16 Bs[4][4096];

    const int tid = threadIdx.x;
    const int lane = tid & 63;
    const int w = tid >> 6;

    // ---- staging: slots q = c*256+tid cover LDS bytes q*16; inverse-swizzled source ----
    const int cp = tid & 3;
    const int rp0 = tid >> 2, rp1 = 64 + rp0;
    const int r0s = rp0 ^ ((rp0 >> 2) & 1);
    const int r1s = rp1 ^ ((rp1 >> 2) & 1);
    const int cc0 = cp ^ (r0s & 3);
    const int cc1 = cp ^ (r1s & 3);
    const u16* pA0 = A + (size_t)list[min(r0s, nvalid - 1)] * KD + ksoff + cc0 * 8;
    const u16* pA1 = A + (size_t)list[min(r1s, nvalid - 1)] * KD + ksoff + cc1 * 8;
    const u16* Bbase = Bt + ((size_t)e * NCOL + (size_t)ct * 128) * KD + ksoff;
    const u16* pB0 = Bbase + (size_t)r0s * KD + cc0 * 8;
    const u16* pB1 = Bbase + (size_t)r1s * KD + cc1 * 8;
    const int dst0 = w * 512;            // u16 offset; HW adds lane*16B
    const int dst1 = 2048 + w * 512;

    const int wm = w >> 1, wn = w & 1;
    const int fr = lane & 15, fg = lane >> 4;
    const int laneoff = (fr * 64 + fg * 16) ^ ((fr & 7) << 4);

    f32x4 acc[4][4];
    #pragma unroll
    for (int i = 0; i < 4; i++)
        #pragma unroll
        for (int j = 0; j < 4; j++) acc[i][j] = (f32x4){0.f, 0.f, 0.f, 0.f};

    auto stage = [&](int T) {
        const int b = T & 3, ko = T * 32;
        GLD_LDS16(pA0 + ko, &As[b][dst0]);
        GLD_LDS16(pA1 + ko, &As[b][dst1]);
        GLD_LDS16(pB0 + ko, &Bs[b][dst0]);
        GLD_LDS16(pB1 + ko, &Bs[b][dst1]);
    };
    auto compute = [&](int T) {
        const char* Ab = (const char*)&As[T & 3][0];
        const char* Bb = (const char*)&Bs[T & 3][0];
        bf16x8 af[4], bg[4];
        #pragma unroll
        for (int m4 = 0; m4 < 4; m4++)
            af[m4] = *(const bf16x8*)(Ab + wm * 4096 + m4 * 1024 + laneoff);
        #pragma unroll
        for (int n4 = 0; n4 < 4; n4++)
            bg[n4] = *(const bf16x8*)(Bb + wn * 4096 + n4 * 1024 + laneoff);
        #pragma unroll
        for (int m4 = 0; m4 < 4; m4++)
            #pragma unroll
            for (int n4 = 0; n4 < 4; n4++)
                acc[m4][n4] = __builtin_amdgcn_mfma_f32_16x16x32_bf16(
                    af[m4], bg[n4], acc[m4][n4], 0, 0, 0);
    };

    // prologue: tiles 0,1,2 in flight (12 vmem ops/wave)
    stage(0); stage(1); stage(2);

    // per iter: wait own tile-t loads (keep t+1,t+2 in flight), barrier, prefetch t+3, compute t
#define GEMM_STEP(T, VW)                                            \
    do {                                                            \
        asm volatile("s_waitcnt vmcnt(%0)" ::"n"(VW) : "memory");   \
        __builtin_amdgcn_sched_barrier(0);                          \
        __builtin_amdgcn_s_barrier();                               \
        __builtin_amdgcn_sched_barrier(0);                          \
        if ((T) + 3 < NS) stage((T) + 3);                           \
        compute(T);                                                 \
    } while (0)

    for (int t = 0; t < NS - 2; ++t) GEMM_STEP(t, 8);
    GEMM_STEP(NS - 2, 4);
    GEMM_STEP(NS - 1, 0);
#undef GEMM_STEP

    // ---- epilogue: C/D layout col = lane&15 (fr), row = fg*4 + reg ----
    #pragma unroll
    for (int m4 = 0; m4 < 4; m4++) {
        const int rowbase = wm * 64 + m4 * 16 + fg * 4;
        #pragma unroll
        for (int r2 = 0; r2 < 4; r2++) {
            const int row = rowbase + r2;
            if (row < nvalid) {
                const int tok = list[row];
                #pragma unroll
                for (int n4 = 0; n4 < 4; n4++) {
                    const int col = ct * 128 + wn * 64 + n4 * 16 + fr;
                    float v = acc[m4][n4][r2];
                    if (GELU_EP) {
                        v += bias[e * NCOL + col];
                        v = 0.5f * v * (1.f + fast_erff(v * 0.70710678118654752f));
                        Hout[(size_t)tok * NCOL + col] = f2bf(v);
                    } else {
                        atomicAdd(&Fout[(size_t)tok * NCOL + col], v);
                    }
                }
            }
        }
    }
}

extern "C" void kernel_launch(void* const* d_in, const int* in_sizes, int n_in,
                              void* d_out, int out_size, void* d_ws, size_t ws_size,
                              hipStream_t stream) {
    const float* x  = (const float*)d_in[0];
    const float* gw = (const float*)d_in[3];
    const float* W1 = (const float*)d_in[4];
    const float* b1 = (const float*)d_in[5];
    const float* W2 = (const float*)d_in[6];
    const float* b2 = (const float*)d_in[7];
    float* out = (float*)d_out;

    char* ws = (char*)d_ws;
    size_t o = 0;
    auto alloc = [&](size_t bytes) -> void* {
        void* p = ws + o;
        o = (o + bytes + 255) & ~(size_t)255;
        return p;
    };
    u16*   xbf    = (u16*)alloc((size_t)NTOK * DIM * 2);
    u16*   W1t    = (u16*)alloc((size_t)NE * DIM * FF * 2);
    u16*   W2t    = (u16*)alloc((size_t)NE * DIM * FF * 2);
    u16*   hbuf   = (u16*)alloc((size_t)NTOK * FF * 2);
    float* probs  = (float*)alloc((size_t)NTOK * 4 * 4);
    int*   tlist  = (int*)alloc((size_t)NE * NTOK * 4);
    int*   eid    = (int*)alloc((size_t)NTOK * 4);
    int*   counts = (int*)alloc(256);

    hipMemsetAsync(counts, 0, 256, stream);
    gate_kernel<<<NTOK / 4, 256, 0, stream>>>(x, gw, probs, counts, tlist, eid);
    finalize_kernel<<<1, 256, 0, stream>>>((const float4*)probs, counts,
                                           out + (size_t)NTOK * DIM);
    convert_x_kernel<<<(NTOK * DIM / 4) / 256, 256, 0, stream>>>((const float4*)x, xbf);
    transpose_convert_kernel<<<dim3(FF / 64, DIM / 64, NE), 256, 0, stream>>>(W1, W1t, DIM, FF);
    transpose_convert_kernel<<<dim3(DIM / 64, FF / 64, NE), 256, 0, stream>>>(W2, W2t, FF, DIM);
    init_out_kernel<<<(NTOK * DIM / 4) / 256, 256, 0, stream>>>(b2, eid, (float4*)out);

    // GEMM1: K=768, N=3072 -> grid 4e*24ct*32rt = 3072
    moe_gemm<DIM, FF, 1, 1><<<NE * (FF / 128) * 32, 256, 0, stream>>>(
        xbf, W1t, b1, counts, tlist, hbuf, nullptr);
    // GEMM2: K=3072 split 4, N=768 -> grid 4e*6ct*4ks*32rt = 3072
    moe_gemm<FF, DIM, 4, 0><<<NE * (DIM / 128) * 4 * 32, 256, 0, stream>>>(
        hbuf, W2t, b2, counts, tlist, nullptr, out);
}

// Round 4
// 191.358 us; speedup vs baseline: 1.2573x; 1.2573x over previous
//
#include <hip/hip_runtime.h>
#include <hip/hip_bf16.h>
#include <stdint.h>
#include <math.h>

#define NTOK 4096
#define DIM 768
#define FF 3072
#define NE 4

typedef __attribute__((ext_vector_type(8))) short bf16x8;
typedef __attribute__((ext_vector_type(4))) float f32x4;
typedef unsigned short u16;

static __device__ __forceinline__ u16 f2bf(float f) {
    union { float f; unsigned u; } c; c.f = f;
    unsigned r = (c.u + 0x7FFFu + ((c.u >> 16) & 1u)) >> 16;
    return (u16)r;
}

// Abramowitz-Stegun 7.1.26, |abs err| <= 1.5e-7 (beyond bf16 grain)
static __device__ __forceinline__ float fast_erff(float x) {
    float ax = fabsf(x);
    float t = 1.0f / (1.0f + 0.3275911f * ax);
    float p = ((((1.061405429f * t - 1.453152027f) * t) + 1.421413741f) * t
               - 0.284496736f) * t + 0.254829592f;
    float y = 1.0f - p * t * __expf(-ax * ax);
    return copysignf(y, x);
}

#define GLD_LDS16(g, l) __builtin_amdgcn_global_load_lds( \
    (const __attribute__((address_space(1))) void*)(g),   \
    (__attribute__((address_space(3))) void*)(l), 16, 0, 0)

// ------- gating (fused with x->bf16 conversion): logits, softmax, argmax, lists -------
__global__ __launch_bounds__(256) void gate_kernel(
    const float* __restrict__ x, const float* __restrict__ gw,
    float* __restrict__ probs, int* __restrict__ counts, int* __restrict__ tlist,
    int* __restrict__ eid, u16* __restrict__ xbf)
{
    const int wid = threadIdx.x >> 6, lane = threadIdx.x & 63;
    const int n = blockIdx.x * 4 + wid;
    const float4* xr4 = (const float4*)(x + (size_t)n * DIM);
    float a0 = 0.f, a1 = 0.f, a2 = 0.f, a3 = 0.f;
    float4 xv[3];
    #pragma unroll
    for (int c = 0; c < 3; c++) {
        float4 v = xr4[c * 64 + lane];
        xv[c] = v;
        const float4 g0 = ((const float4*)(gw + 0 * DIM))[c * 64 + lane];
        const float4 g1 = ((const float4*)(gw + 1 * DIM))[c * 64 + lane];
        const float4 g2 = ((const float4*)(gw + 2 * DIM))[c * 64 + lane];
        const float4 g3 = ((const float4*)(gw + 3 * DIM))[c * 64 + lane];
        a0 += v.x * g0.x + v.y * g0.y + v.z * g0.z + v.w * g0.w;
        a1 += v.x * g1.x + v.y * g1.y + v.z * g1.z + v.w * g1.w;
        a2 += v.x * g2.x + v.y * g2.y + v.z * g2.z + v.w * g2.w;
        a3 += v.x * g3.x + v.y * g3.y + v.z * g3.z + v.w * g3.w;
    }
    #pragma unroll
    for (int c = 0; c < 3; c++) {
        ushort4 o;
        o.x = f2bf(xv[c].x); o.y = f2bf(xv[c].y);
        o.z = f2bf(xv[c].z); o.w = f2bf(xv[c].w);
        *(ushort4*)(xbf + (size_t)n * DIM + (c * 64 + lane) * 4) = o;
    }
    #pragma unroll
    for (int off = 32; off > 0; off >>= 1) {
        a0 += __shfl_xor(a0, off);
        a1 += __shfl_xor(a1, off);
        a2 += __shfl_xor(a2, off);
        a3 += __shfl_xor(a3, off);
    }
    if (lane == 0) {
        float l[4] = {a0, a1, a2, a3};
        float m = fmaxf(fmaxf(l[0], l[1]), fmaxf(l[2], l[3]));
        float p[4], s = 0.f;
        #pragma unroll
        for (int e = 0; e < 4; e++) { p[e] = expf(l[e] - m); s += p[e]; }
        float inv = 1.f / s;
        int amax = 0; float best = l[0];
        #pragma unroll
        for (int e = 1; e < 4; e++) if (l[e] > best) { best = l[e]; amax = e; }
        #pragma unroll
        for (int e = 0; e < 4; e++) probs[n * 4 + e] = p[e] * inv;
        eid[n] = amax;
        int pos = atomicAdd(&counts[amax], 1);
        tlist[amax * NTOK + pos] = n;
    }
}

// ---------------- balance loss + gate_load tail outputs ----------------
__global__ __launch_bounds__(256) void finalize_kernel(
    const float4* __restrict__ probs4, const int* __restrict__ counts,
    float* __restrict__ tail)
{
    __shared__ float sdata[256 * 4];
    float p0 = 0.f, p1 = 0.f, p2 = 0.f, p3 = 0.f;
    for (int n = threadIdx.x; n < NTOK; n += 256) {
        float4 v = probs4[n];
        p0 += v.x; p1 += v.y; p2 += v.z; p3 += v.w;
    }
    sdata[threadIdx.x * 4 + 0] = p0;
    sdata[threadIdx.x * 4 + 1] = p1;
    sdata[threadIdx.x * 4 + 2] = p2;
    sdata[threadIdx.x * 4 + 3] = p3;
    __syncthreads();
    for (int s = 128; s > 0; s >>= 1) {
        if ((int)threadIdx.x < s) {
            #pragma unroll
            for (int e = 0; e < 4; e++)
                sdata[threadIdx.x * 4 + e] += sdata[(threadIdx.x + s) * 4 + e];
        }
        __syncthreads();
    }
    if (threadIdx.x == 0) {
        float bl = 0.f;
        #pragma unroll
        for (int e = 0; e < 4; e++)
            bl += (sdata[e] / (float)NTOK) * ((float)counts[e] / (float)NTOK);
        bl *= (float)NE;
        tail[0] = bl;
        #pragma unroll
        for (int e = 0; e < 4; e++) tail[1 + e] = (float)counts[e];
    }
}

// ---- fp32 [E][R][C] -> bf16 [E][C][R] transpose, vectorized both sides ----
__global__ __launch_bounds__(256) void transpose_convert_kernel(
    const float* __restrict__ in, u16* __restrict__ out, int R, int C)
{
    __shared__ float tile[64 * 65];
    const int e = blockIdx.z;
    const float* src = in + (size_t)e * R * C;
    u16* dst = out + (size_t)e * R * C;
    const int r0 = blockIdx.y * 64, c0 = blockIdx.x * 64;
    #pragma unroll
    for (int p = 0; p < 4; ++p) {
        int f = p * 256 + threadIdx.x;
        int row = f >> 4, c4 = (f & 15) * 4;
        float4 v = *(const float4*)(src + (size_t)(r0 + row) * C + c0 + c4);
        tile[row * 65 + c4 + 0] = v.x;
        tile[row * 65 + c4 + 1] = v.y;
        tile[row * 65 + c4 + 2] = v.z;
        tile[row * 65 + c4 + 3] = v.w;
    }
    __syncthreads();
    #pragma unroll
    for (int p = 0; p < 2; ++p) {
        int u = p * 256 + threadIdx.x;
        int orow = u >> 3, g = (u & 7) * 8;
        bf16x8 v;
        #pragma unroll
        for (int j = 0; j < 8; ++j)
            v[j] = (short)f2bf(tile[(g + j) * 65 + orow]);
        *(bf16x8*)(dst + (size_t)(c0 + orow) * R + r0 + g) = v;
    }
}

// ---------------- out := bias row per token's expert (split-K atomic base) ----------------
__global__ __launch_bounds__(256) void init_out_kernel(
    const float* __restrict__ b2, const int* __restrict__ eid,
    float4* __restrict__ out4)
{
    int idx = blockIdx.x * 256 + threadIdx.x;
    int n = idx / (DIM / 4);
    int c = idx % (DIM / 4);
    int e = eid[n];
    out4[idx] = ((const float4*)(b2 + (size_t)e * DIM))[c];
}

// ---- grouped MFMA GEMM, 128x128 tile, 4 waves, depth-2 counted-vmcnt, 3 LDS bufs ----
// XCD-pinned (xcd = blockIdx&7):
//   MODE 0 (GEMM1): e = xcd>>1, ct = (xcd&1)*CTN/2 + local>>5, rt = local&31.
//   MODE 1 (GEMM2): e = xcd>>1, ks = xcd&1, rt = local/CTN, ct = local%CTN.
template <int KD, int NCOL, int KSPLIT, int GELU_EP, int MODE>
__global__ __launch_bounds__(256, 3) void moe_gemm(
    const u16* __restrict__ A, const u16* __restrict__ Bt,
    const float* __restrict__ bias, const int* __restrict__ counts,
    const int* __restrict__ tlist, u16* __restrict__ Hout,
    float* __restrict__ Fout)
{
    constexpr int KSUB = KD / KSPLIT;
    constexpr int NS = KSUB / 32;
    constexpr int CTN = NCOL / 128;

    const int xcd = blockIdx.x & 7;
    const int local = blockIdx.x >> 3;
    const int e = xcd >> 1;
    int ct, ks, rt;
    if (MODE == 0) {
        ks = 0;
        ct = (xcd & 1) * (CTN / 2) + (local >> 5);
        rt = local & 31;
    } else {
        ks = xcd & 1;
        rt = local / CTN;
        ct = local % CTN;
    }

    const int cnt = counts[e];
    if (rt * 128 >= cnt) return;
    const int nvalid = min(128, cnt - rt * 128);
    const int* list = tlist + e * NTOK + rt * 128;
    const int ksoff = ks * KSUB;

    __shared__ __align__(16) u16 As[3][4096];
    __shared__ __align__(16) u16 Bs[3][4096];

    const int tid = threadIdx.x;
    const int lane = tid & 63;
    const int w = tid >> 6;

    // staging: slots q = c*256+tid cover LDS bytes q*16; inverse-swizzled source
    const int cp = tid & 3;
    const int rp0 = tid >> 2, rp1 = 64 + rp0;
    const int r0s = rp0 ^ ((rp0 >> 2) & 1);
    const int r1s = rp1 ^ ((rp1 >> 2) & 1);
    const int cc0 = cp ^ (r0s & 3);
    const int cc1 = cp ^ (r1s & 3);
    const u16* pA0 = A + (size_t)list[min(r0s, nvalid - 1)] * KD + ksoff + cc0 * 8;
    const u16* pA1 = A + (size_t)list[min(r1s, nvalid - 1)] * KD + ksoff + cc1 * 8;
    const u16* Bbase = Bt + ((size_t)e * NCOL + (size_t)ct * 128) * KD + ksoff;
    const u16* pB0 = Bbase + (size_t)r0s * KD + cc0 * 8;
    const u16* pB1 = Bbase + (size_t)r1s * KD + cc1 * 8;
    const int dst0 = w * 512;
    const int dst1 = 2048 + w * 512;

    const int wm = w >> 1, wn = w & 1;
    const int fr = lane & 15, fg = lane >> 4;
    const int laneoff = (fr * 64 + fg * 16) ^ ((fr & 7) << 4);

    f32x4 acc[4][4];
    #pragma unroll
    for (int i = 0; i < 4; i++)
        #pragma unroll
        for (int j = 0; j < 4; j++) acc[i][j] = (f32x4){0.f, 0.f, 0.f, 0.f};

    auto stage = [&](int T) {
        const int b = T % 3, ko = T * 32;
        GLD_LDS16(pA0 + ko, &As[b][dst0]);
        GLD_LDS16(pA1 + ko, &As[b][dst1]);
        GLD_LDS16(pB0 + ko, &Bs[b][dst0]);
        GLD_LDS16(pB1 + ko, &Bs[b][dst1]);
    };
    auto compute = [&](int T) {
        const char* Ab = (const char*)&As[T % 3][0];
        const char* Bb = (const char*)&Bs[T % 3][0];
        bf16x8 af[4], bg[4];
        #pragma unroll
        for (int m4 = 0; m4 < 4; m4++)
            af[m4] = *(const bf16x8*)(Ab + wm * 4096 + m4 * 1024 + laneoff);
        #pragma unroll
        for (int n4 = 0; n4 < 4; n4++)
            bg[n4] = *(const bf16x8*)(Bb + wn * 4096 + n4 * 1024 + laneoff);
        #pragma unroll
        for (int m4 = 0; m4 < 4; m4++)
            #pragma unroll
            for (int n4 = 0; n4 < 4; n4++)
                acc[m4][n4] = __builtin_amdgcn_mfma_f32_16x16x32_bf16(
                    af[m4], bg[n4], acc[m4][n4], 0, 0, 0);
    };

    // prologue: tiles 0,1 in flight (8 vmem ops/wave)
    stage(0); stage(1);

    for (int t = 0; t < NS; ++t) {
        // drain own tile-t loads; keep tile t+1's 4 in flight (except last step)
        if (t < NS - 1)
            asm volatile("s_waitcnt vmcnt(4)" ::: "memory");
        else
            asm volatile("s_waitcnt vmcnt(0)" ::: "memory");
        __builtin_amdgcn_sched_barrier(0);
        __builtin_amdgcn_s_barrier();
        __builtin_amdgcn_sched_barrier(0);
        if (t + 2 < NS) stage(t + 2);
        compute(t);
    }

    // ---- epilogue: C/D layout col = lane&15 (fr), row = fg*4 + reg ----
    #pragma unroll
    for (int m4 = 0; m4 < 4; m4++) {
        const int rowbase = wm * 64 + m4 * 16 + fg * 4;
        #pragma unroll
        for (int r2 = 0; r2 < 4; r2++) {
            const int row = rowbase + r2;
            if (row < nvalid) {
                const int tok = list[row];
                #pragma unroll
                for (int n4 = 0; n4 < 4; n4++) {
                    const int col = ct * 128 + wn * 64 + n4 * 16 + fr;
                    float v = acc[m4][n4][r2];
                    if (GELU_EP) {
                        v += bias[e * NCOL + col];
                        v = 0.5f * v * (1.f + fast_erff(v * 0.70710678118654752f));
                        Hout[(size_t)tok * NCOL + col] = f2bf(v);
                    } else {
                        atomicAdd(&Fout[(size_t)tok * NCOL + col], v);
                    }
                }
            }
        }
    }
}

extern "C" void kernel_launch(void* const* d_in, const int* in_sizes, int n_in,
                              void* d_out, int out_size, void* d_ws, size_t ws_size,
                              hipStream_t stream) {
    const float* x  = (const float*)d_in[0];
    const float* gw = (const float*)d_in[3];
    const float* W1 = (const float*)d_in[4];
    const float* b1 = (const float*)d_in[5];
    const float* W2 = (const float*)d_in[6];
    const float* b2 = (const float*)d_in[7];
    float* out = (float*)d_out;

    char* ws = (char*)d_ws;
    size_t o = 0;
    auto alloc = [&](size_t bytes) -> void* {
        void* p = ws + o;
        o = (o + bytes + 255) & ~(size_t)255;
        return p;
    };
    u16*   xbf    = (u16*)alloc((size_t)NTOK * DIM * 2);
    u16*   W1t    = (u16*)alloc((size_t)NE * DIM * FF * 2);
    u16*   W2t    = (u16*)alloc((size_t)NE * DIM * FF * 2);
    u16*   hbuf   = (u16*)alloc((size_t)NTOK * FF * 2);
    float* probs  = (float*)alloc((size_t)NTOK * 4 * 4);
    int*   tlist  = (int*)alloc((size_t)NE * NTOK * 4);
    int*   eid    = (int*)alloc((size_t)NTOK * 4);
    int*   counts = (int*)alloc(256);

    hipMemsetAsync(counts, 0, 256, stream);
    gate_kernel<<<NTOK / 4, 256, 0, stream>>>(x, gw, probs, counts, tlist, eid, xbf);
    finalize_kernel<<<1, 256, 0, stream>>>((const float4*)probs, counts,
                                           out + (size_t)NTOK * DIM);
    transpose_convert_kernel<<<dim3(FF / 64, DIM / 64, NE), 256, 0, stream>>>(W1, W1t, DIM, FF);
    transpose_convert_kernel<<<dim3(DIM / 64, FF / 64, NE), 256, 0, stream>>>(W2, W2t, FF, DIM);
    init_out_kernel<<<(NTOK * DIM / 4) / 256, 256, 0, stream>>>(b2, eid, (float4*)out);

    // GEMM1: K=768, N=3072. grid = 8 xcd * 12 ctl * 32 rt = 3072
    moe_gemm<DIM, FF, 1, 1, 0><<<8 * 12 * 32, 256, 0, stream>>>(
        xbf, W1t, b1, counts, tlist, hbuf, nullptr);
    // GEMM2: K=3072 split 2 (ks = xcd&1), N=768. grid = 8 xcd * 32 rt * 6 ct = 1536
    moe_gemm<FF, DIM, 2, 0, 1><<<8 * 32 * 6, 256, 0, stream>>>(
        hbuf, W2t, b2, counts, tlist, nullptr, out);
}